// Round 11
// baseline (174.702 us; speedup 1.0000x reference)
//
#include <hip/hip_runtime.h>

typedef __bf16 bf16x8 __attribute__((ext_vector_type(8)));
typedef float f32x4 __attribute__((ext_vector_type(4)));

#define D_MODEL 768
#define NH 12
#define DKH 64
#define BATCH 4
#define SEQ 2048
#define ROWS (BATCH*SEQ)   /* 8192 */
#define N_QKV (3*D_MODEL)  /* 2304 */
#define QSCALE 0.18033688f /* 0.125 * log2(e): folds softmax scale + exp2 domain into Q */

// ---------------- convert fp32 -> bf16 ----------------
__global__ void k_convert(const float* __restrict__ in, __bf16* __restrict__ out, int n) {
  int i = (blockIdx.x * blockDim.x + threadIdx.x) * 4;
  if (i >= n) return;
  float4 v = *(const float4*)(in + i);
  out[i+0] = (__bf16)v.x; out[i+1] = (__bf16)v.y;
  out[i+2] = (__bf16)v.z; out[i+3] = (__bf16)v.w;
}

// ---------------- transpose fp32 [R][C] -> bf16 [C][R] ----------------
__global__ void k_transpose(const float* __restrict__ in, __bf16* __restrict__ out, int R, int C) {
  __shared__ float tile[32][33];
  int c0 = blockIdx.x * 32, r0 = blockIdx.y * 32;
  int tx = threadIdx.x, ty = threadIdx.y;   // (32, 8)
  #pragma unroll
  for (int i = 0; i < 4; ++i) {
    int r = ty + i*8;
    tile[r][tx] = in[(size_t)(r0 + r)*C + c0 + tx];
  }
  __syncthreads();
  #pragma unroll
  for (int i = 0; i < 4; ++i) {
    int c = ty + i*8;
    out[(size_t)(c0 + c)*R + r0 + tx] = (__bf16)tile[tx][c];
  }
}

// ---------------- GEMM stage: one 128x32 A-tile + B-tile via global_load_lds ----------------
// Per wave: 4 loads (2 A-chunks + 2 B-chunks of 1KB).
__device__ __forceinline__ void gemm_stage(const __bf16* __restrict__ A, int lda,
                                           const __bf16* __restrict__ Bt, int ldb,
                                           int m0, int n0, int kt,
                                           __bf16* lA, __bf16* lB) {
  const int tid  = threadIdx.x;
  const int lane = tid & 63;
  const int wid  = tid >> 6;
  #pragma unroll
  for (int c = 0; c < 2; ++c) {
    int chunk = wid*2 + c;               // 0..7
    int bo = chunk*1024 + lane*16;       // byte offset in tile
    int m  = bo >> 6;                    // 64B per row
    int kb = (bo & 63) >> 1;             // element in row
    __builtin_amdgcn_global_load_lds(
      (const __attribute__((address_space(1))) void*)(A + (size_t)(m0 + m)*lda + kt + kb),
      (__attribute__((address_space(3))) void*)(lA + chunk*512), 16, 0, 0);
    __builtin_amdgcn_global_load_lds(
      (const __attribute__((address_space(1))) void*)(Bt + (size_t)(n0 + m)*ldb + kt + kb),
      (__attribute__((address_space(3))) void*)(lB + chunk*512), 16, 0, 0);
  }
}

// ---------------- GEMM core: triple-buffer, counted-vmcnt pipeline (T4) ----------------
// Never drains vmcnt to 0 in the main loop: iteration t waits vmcnt(4) (own tile-t
// loads retired, tile-t+1's 4 loads stay in flight), raw s_barrier (all waves'
// t-loads visible; all waves done computing t-1), then stages t+2 into the buffer
// t-1 just vacated. LDS 3x(8KB+8KB) = 48KB -> 3 blocks/CU.
__device__ __forceinline__ void gemm_core(const __bf16* __restrict__ A, int lda,
                                          const __bf16* __restrict__ Bt, int ldb,
                                          int K, int m0, int n0,
                                          __bf16* lA, __bf16* lB, f32x4 acc[4][4]) {
  const int lane = threadIdx.x & 63;
  const int wid  = threadIdx.x >> 6;
  const int wm   = (wid >> 1) * 64;
  const int wn   = (wid & 1) * 64;
  const int lr   = lane & 15;
  const int lk   = lane >> 4;
  const int NT   = K >> 5;             // K/32 tiles

  gemm_stage(A, lda, Bt, ldb, m0, n0, 0, lA, lB);
  if (NT > 1)
    gemm_stage(A, lda, Bt, ldb, m0, n0, 32, lA + 4096, lB + 4096);

  for (int t = 0; t < NT; ++t) {
    if (t + 1 < NT) asm volatile("s_waitcnt vmcnt(4)" ::: "memory");
    else            asm volatile("s_waitcnt vmcnt(0)" ::: "memory");
    __builtin_amdgcn_s_barrier();
    __builtin_amdgcn_sched_barrier(0);
    if (t + 2 < NT) {
      int nb = (t + 2) % 3;
      gemm_stage(A, lda, Bt, ldb, m0, n0, (t+2)*32, lA + nb*4096, lB + nb*4096);
    }
    const __bf16* cA = lA + (t % 3)*4096;
    const __bf16* cB = lB + (t % 3)*4096;
    bf16x8 af[4], bfr[4];
    #pragma unroll
    for (int i = 0; i < 4; ++i) {
      af[i]  = *(const bf16x8*)(cA + (wm + i*16 + lr)*32 + lk*8);
      bfr[i] = *(const bf16x8*)(cB + (wn + i*16 + lr)*32 + lk*8);
    }
    #pragma unroll
    for (int mi = 0; mi < 4; ++mi)
      #pragma unroll
      for (int ni = 0; ni < 4; ++ni)
        acc[mi][ni] = __builtin_amdgcn_mfma_f32_16x16x32_bf16(af[mi], bfr[ni], acc[mi][ni], 0, 0, 0);
    // no trailing barrier: next iteration's s_barrier (after its vmcnt wait)
    // orders buffer reuse; MFMA reads complete before this wave re-enters barrier.
  }
}

// ---------------- GEMM1: qkv = xb @ WqkvT + bqkv, scatter to Q(scaled),K,V^T(pi) ----------------
// V^T stored PI-PERMUTED within each 32-seq granule: position p holds seq
// kv = 16*((p>>2)&1) + 4*((p>>3)&3) + (p&3). Attention PV B-fragment becomes a
// contiguous ds_read_b128 (conflict-free).
__global__ __launch_bounds__(256) void k_gemm_qkv(const __bf16* __restrict__ xb,
                                                  const __bf16* __restrict__ wT,
                                                  const float* __restrict__ bias,
                                                  __bf16* __restrict__ qb,
                                                  __bf16* __restrict__ kb,
                                                  __bf16* __restrict__ vtb) {
  __shared__ __align__(16) __bf16 lA[3*128*32];
  __shared__ __align__(16) __bf16 lB[3*128*32];
  f32x4 acc[4][4];
  #pragma unroll
  for (int i = 0; i < 4; ++i)
    #pragma unroll
    for (int j = 0; j < 4; ++j) { f32x4 z = {0.f,0.f,0.f,0.f}; acc[i][j] = z; }

  const int GX = N_QKV/128;  // 18
  int bid = blockIdx.y * GX + blockIdx.x;
  int cpx = (GX * ROWS/128) >> 3;
  int swz = (bid & 7) * cpx + (bid >> 3);
  const int m0 = (swz / GX) * 128, n0 = (swz % GX) * 128;
  gemm_core(xb, D_MODEL, wT, D_MODEL, D_MODEL, m0, n0, lA, lB, acc);

  const int lane = threadIdx.x & 63;
  const int wid  = threadIdx.x >> 6;
  const int wm = (wid >> 1) * 64, wn = (wid & 1) * 64;
  const int lr = lane & 15, lk = lane >> 4;
  #pragma unroll
  for (int mi = 0; mi < 4; ++mi) {
    #pragma unroll
    for (int ni = 0; ni < 4; ++ni) {
      int col = n0 + wn + ni*16 + lr;
      int t   = col / D_MODEL;
      int r2  = col - t*D_MODEL;
      int hh  = r2 >> 6, dk = r2 & 63;
      float bv = bias[col];
      #pragma unroll
      for (int j = 0; j < 4; ++j) {
        int row = m0 + wm + mi*16 + lk*4 + j;
        int bb = row >> 11, ss = row & 2047;
        float fv = acc[mi][ni][j] + bv;
        if (t == 0)      qb [(((size_t)bb*NH + hh)*SEQ + ss)*DKH + dk] = (__bf16)(fv * QSCALE);
        else if (t == 1) kb [(((size_t)bb*NH + hh)*SEQ + ss)*DKH + dk] = (__bf16)fv;
        else {
          // pi-permuted position within the 32-seq granule
          int ssp = (ss & ~31) | (lk << 3) | ((mi & 1) << 2) | j;
          vtb[(((size_t)bb*NH + hh)*DKH + dk)*SEQ + ssp] = (__bf16)fv;
        }
      }
    }
  }
}

// ---------------- GEMM3: out = attn @ WoutT + bout (fp32 out) ----------------
__global__ __launch_bounds__(256) void k_gemm_out(const __bf16* __restrict__ ab,
                                                  const __bf16* __restrict__ wT,
                                                  const float* __restrict__ bias,
                                                  float* __restrict__ out) {
  __shared__ __align__(16) __bf16 lA[3*128*32];
  __shared__ __align__(16) __bf16 lB[3*128*32];
  f32x4 acc[4][4];
  #pragma unroll
  for (int i = 0; i < 4; ++i)
    #pragma unroll
    for (int j = 0; j < 4; ++j) { f32x4 z = {0.f,0.f,0.f,0.f}; acc[i][j] = z; }

  const int GX = D_MODEL/128;  // 6
  int bid = blockIdx.y * GX + blockIdx.x;
  int cpx = (GX * ROWS/128) >> 3;
  int swz = (bid & 7) * cpx + (bid >> 3);
  const int m0 = (swz / GX) * 128, n0 = (swz % GX) * 128;
  gemm_core(ab, D_MODEL, wT, D_MODEL, D_MODEL, m0, n0, lA, lB, acc);

  const int lane = threadIdx.x & 63;
  const int wid  = threadIdx.x >> 6;
  const int wm = (wid >> 1) * 64, wn = (wid & 1) * 64;
  const int lr = lane & 15, lk = lane >> 4;
  #pragma unroll
  for (int mi = 0; mi < 4; ++mi) {
    #pragma unroll
    for (int ni = 0; ni < 4; ++ni) {
      int col = n0 + wn + ni*16 + lr;
      float bv = bias[col];
      #pragma unroll
      for (int j = 0; j < 4; ++j) {
        int row = m0 + wm + mi*16 + lk*4 + j;
        out[(size_t)row*D_MODEL + col] = acc[mi][ni][j] + bv;
      }
    }
  }
}

// Balanced qi map: three permutations of 0..15 with column sums 22/23 (per-CU
// causal work ~constant under round-robin block->CU assignment).
__device__ const int QI_TAB[3][16] = {
  { 0, 1, 2, 3, 4, 5, 6, 7, 8, 9,10,11,12,13,14,15},
  { 8, 9,10,11,12,13,14,15, 1, 2, 3, 4, 5, 6, 7, 0},
  {15,13,11, 9, 6, 4, 2, 0,14,12,10, 7, 5, 3, 1, 8}
};

// ---------------- Flash attention (causal), 8 waves x 16 q-rows ----------------
// grid (16, 48), 512 thr = 8 waves; block owns 128 q-rows (wave: 16), KVBLK=64.
// K/V^T LDS dbuf (16B-granule swizzle). Swapped QK^T (mfma(K,Q) -> S^T), in-lane
// softmax, in-register P. V^T global layout is pi-permuted (see k_gemm_qkv) so
// the PV B-fragment is ONE ds_read_b128 (conflict-free, same pattern as K).
// Row-sum l via MFMA-with-ones into o_l (same C-layout as O -> shuffle-free
// epilogue). Q pre-scaled (exp2 domain). setprio around MFMA clusters.
__global__ __launch_bounds__(512) void k_attn(const __bf16* __restrict__ q,
                                              const __bf16* __restrict__ k,
                                              const __bf16* __restrict__ vt,
                                              __bf16* __restrict__ out) {
  __shared__ __align__(16) char lsK[2][8192];   // [64 kv][64 d] bf16, swizzled rows
  __shared__ __align__(16) char lsV[2][8192];   // [64 d][64 kv-pi] bf16, swizzled rows

  const int tid  = threadIdx.x;
  const int lane = tid & 63;
  const int wid  = tid >> 6;       // 0..7
  const int lr   = lane & 15;
  const int lk   = lane >> 4;

  const int bh = blockIdx.y;
  const int b  = bh / NH, h = bh - b*NH;
  const int qi  = QI_TAB[blockIdx.y >> 4][blockIdx.x];
  const int qb0 = qi * 128;
  const int q0w = qb0 + wid * 16;

  const __bf16* qh = q + (size_t)bh*SEQ*DKH;
  const char*   kB = (const char*)(k  + (size_t)bh*SEQ*DKH);
  const char*   vB = (const char*)(vt + (size_t)bh*DKH*SEQ);

  // Q fragments (B-operand of swapped QK): lane holds Q[q0w+lr][32c + 8lk .. +7]
  bf16x8 bq[2];
  #pragma unroll
  for (int c = 0; c < 2; ++c)
    bq[c] = *(const bf16x8*)(qh + (size_t)(q0w + lr)*DKH + c*32 + lk*8);

  bf16x8 ones;
  #pragma unroll
  for (int i = 0; i < 8; ++i) ones[i] = (__bf16)1.0f;

  // o[df]: rows q = q0w+4lk+j, col d = df*16+lr ; o_l: row sums, same layout
  f32x4 o[4];
  #pragma unroll
  for (int df = 0; df < 4; ++df) { f32x4 z = {0.f,0.f,0.f,0.f}; o[df] = z; }
  f32x4 o_l = {0.f, 0.f, 0.f, 0.f};
  float m_i = -1e30f;               // softmax max for q-row q0w + lr

  const int nt = qb0/64 + 2;        // kv tiles: [0, qb0+128)

  auto stage = [&](int buf, int kv0) {
    int lb   = wid*1024 + lane*16;                // linear dest byte in 8KB tile
    int row  = lb >> 7;                           // 128B rows
    int colb = (lb & 127) ^ ((row & 7) << 4);     // pre-swizzled source column
    __builtin_amdgcn_global_load_lds(
      (const __attribute__((address_space(1))) void*)(kB + (size_t)(kv0 + row)*128 + colb),
      (__attribute__((address_space(3))) void*)(lsK[buf] + wid*1024), 16, 0, 0);
    __builtin_amdgcn_global_load_lds(
      (const __attribute__((address_space(1))) void*)(vB + (size_t)row*(SEQ*2) + (size_t)kv0*2 + colb),
      (__attribute__((address_space(3))) void*)(lsV[buf] + wid*1024), 16, 0, 0);
  };

  stage(0, 0);
  __syncthreads();
  int cur = 0;

  for (int t = 0; t < nt; ++t) {
    const int kv0 = t * 64;
    if (t + 1 < nt) stage(cur ^ 1, kv0 + 64);

    if (kv0 <= q0w + 15) {          // wave-uniform causal activity
      // ---- S^T = K Q^T : C[kv][q]: lane q-col=lr, kv-row=16n+4lk+j ----
      f32x4 sc[4];
      #pragma unroll
      for (int n = 0; n < 4; ++n) { f32x4 z = {0.f,0.f,0.f,0.f}; sc[n] = z; }
      __builtin_amdgcn_s_setprio(1);
      #pragma unroll
      for (int n = 0; n < 4; ++n) {
        int kvl = n*16 + lr;
        const char* kr = lsK[cur] + kvl*128;
        int sw = (kvl & 7) << 4;
        bf16x8 ak0 = *(const bf16x8*)(kr + ((lk*16) ^ sw));       // K[kvl][8lk..], c=0
        bf16x8 ak1 = *(const bf16x8*)(kr + ((64 + lk*16) ^ sw));  // c=1
        sc[n] = __builtin_amdgcn_mfma_f32_16x16x32_bf16(ak0, bq[0], sc[n], 0, 0, 0);
        sc[n] = __builtin_amdgcn_mfma_f32_16x16x32_bf16(ak1, bq[1], sc[n], 0, 0, 0);
      }
      __builtin_amdgcn_s_setprio(0);
      // ---- causal mask (diag tiles only): kv = kv0+16n+4lk+j, q = q0w+lr ----
      if (kv0 + 63 > q0w) {
        int qrow = q0w + lr;
        #pragma unroll
        for (int n = 0; n < 4; ++n) {
          int kvb = kv0 + n*16 + lk*4;
          #pragma unroll
          for (int j = 0; j < 4; ++j)
            if (kvb + j > qrow) sc[n][j] = -1e30f;
        }
      }
      // ---- row max: max3-friendly tree, then 2 cross-group shuffles ----
      float a0 = fmaxf(fmaxf(sc[0][0], sc[0][1]), sc[0][2]);
      float a1 = fmaxf(fmaxf(sc[0][3], sc[1][0]), sc[1][1]);
      float a2 = fmaxf(fmaxf(sc[1][2], sc[1][3]), sc[2][0]);
      float a3 = fmaxf(fmaxf(sc[2][1], sc[2][2]), sc[2][3]);
      float a4 = fmaxf(fmaxf(sc[3][0], sc[3][1]), sc[3][2]);
      float pm = fmaxf(fmaxf(fmaxf(a0, a1), a2), fmaxf(fmaxf(a3, a4), sc[3][3]));
      pm = fmaxf(pm, __shfl_xor(pm, 16));
      pm = fmaxf(pm, __shfl_xor(pm, 32));
      // ---- defer-max (T13) ----
      if (__any(pm > m_i + 8.0f)) {
        float mn = fmaxf(m_i, pm);
        float alpha = exp2f(m_i - mn);
        m_i = mn;
        // o/o_l rows are q=4lk+j: fetch alpha from lane (lane&48)|(4lk+j)
        #pragma unroll
        for (int j = 0; j < 4; ++j) {
          float av = __shfl(alpha, (lane & 48) | (lk*4 + j));
          o_l[j] *= av;
          #pragma unroll
          for (int df = 0; df < 4; ++df) o[df][j] *= av;
        }
      }
      // ---- P = exp2(s - m) in-register; pack PV A-frags (pi order) ----
      bf16x8 pa[2];
      #pragma unroll
      for (int n = 0; n < 4; ++n)
        #pragma unroll
        for (int j = 0; j < 4; ++j)
          pa[n >> 1][((n & 1) << 2) | j] = (__bf16)exp2f(sc[n][j] - m_i);
      // ---- O += P V (V pi-stored: ONE b128 per c); l += P . 1 on MFMA pipe ----
      __builtin_amdgcn_s_setprio(1);
      o_l = __builtin_amdgcn_mfma_f32_16x16x32_bf16(pa[0], ones, o_l, 0, 0, 0);
      o_l = __builtin_amdgcn_mfma_f32_16x16x32_bf16(pa[1], ones, o_l, 0, 0, 0);
      #pragma unroll
      for (int df = 0; df < 4; ++df) {
        int d = df*16 + lr;
        const char* vr = lsV[cur] + d*128;
        int sw = (d & 7) << 4;
        #pragma unroll
        for (int c = 0; c < 2; ++c) {
          bf16x8 bv = *(const bf16x8*)(vr + ((c*64 + lk*16) ^ sw));
          o[df] = __builtin_amdgcn_mfma_f32_16x16x32_bf16(pa[c], bv, o[df], 0, 0, 0);
        }
      }
      __builtin_amdgcn_s_setprio(0);
    }
    __syncthreads();
    cur ^= 1;
  }

  // ---- epilogue: l already in o-row layout -> shuffle-free ----
  float invl[4];
  #pragma unroll
  for (int j = 0; j < 4; ++j) invl[j] = 1.0f / o_l[j];
  #pragma unroll
  for (int df = 0; df < 4; ++df) {
    int d = df*16 + lr;
    #pragma unroll
    for (int j = 0; j < 4; ++j) {
      int ss = q0w + lk*4 + j;
      out[((size_t)b*SEQ + ss)*D_MODEL + h*DKH + d] = (__bf16)(o[df][j] * invl[j]);
    }
  }
}

// ---------------- launch ----------------
extern "C" void kernel_launch(void* const* d_in, const int* in_sizes, int n_in,
                              void* d_out, int out_size, void* d_ws, size_t ws_size,
                              hipStream_t stream) {
  const float* x    = (const float*)d_in[0];
  /* d_in[1] = causal mask, implemented analytically */
  const float* Wqkv = (const float*)d_in[2];
  const float* bqkv = (const float*)d_in[3];
  const float* Wout = (const float*)d_in[4];
  const float* bout = (const float*)d_in[5];
  float* out = (float*)d_out;

  char* w = (char*)d_ws;
  __bf16* xb    = (__bf16*)w; w += (size_t)ROWS*D_MODEL*2;
  __bf16* wqkvT = (__bf16*)w; w += (size_t)N_QKV*D_MODEL*2;
  __bf16* woutT = (__bf16*)w; w += (size_t)D_MODEL*D_MODEL*2;
  __bf16* qb    = (__bf16*)w; w += (size_t)BATCH*NH*SEQ*DKH*2;
  __bf16* kb    = (__bf16*)w; w += (size_t)BATCH*NH*SEQ*DKH*2;
  __bf16* vtb   = (__bf16*)w; w += (size_t)BATCH*NH*SEQ*DKH*2;
  __bf16* attnb = (__bf16*)w; w += (size_t)ROWS*D_MODEL*2;

  k_convert<<<(ROWS*D_MODEL/4 + 255)/256, 256, 0, stream>>>(x, xb, ROWS*D_MODEL);
  k_transpose<<<dim3(N_QKV/32, D_MODEL/32), dim3(32, 8), 0, stream>>>(Wqkv, wqkvT, D_MODEL, N_QKV);
  k_transpose<<<dim3(D_MODEL/32, D_MODEL/32), dim3(32, 8), 0, stream>>>(Wout, woutT, D_MODEL, D_MODEL);
  k_gemm_qkv<<<dim3(N_QKV/128, ROWS/128), 256, 0, stream>>>(xb, wqkvT, bqkv, qb, kb, vtb);
  k_attn<<<dim3(16, BATCH*NH), 512, 0, stream>>>(qb, kb, vtb, attnb);
  k_gemm_out<<<dim3(D_MODEL/128, ROWS/128), 256, 0, stream>>>(attnb, woutT, bout, out);
}

// Round 13
// 153.864 us; speedup vs baseline: 1.1354x; 1.1354x over previous
//
#include <hip/hip_runtime.h>

typedef __bf16 bf16x8 __attribute__((ext_vector_type(8)));
typedef __bf16 bf16x4 __attribute__((ext_vector_type(4)));
typedef float f32x4 __attribute__((ext_vector_type(4)));

#define D_MODEL 768
#define NH 12
#define DKH 64
#define BATCH 4
#define SEQ 2048
#define ROWS (BATCH*SEQ)   /* 8192 */
#define N_QKV (3*D_MODEL)  /* 2304 */
#define QSCALE 0.18033688f /* 0.125 * log2(e): folds softmax scale + exp2 domain into Q */

// ---------------- convert fp32 -> bf16 ----------------
__global__ void k_convert(const float* __restrict__ in, __bf16* __restrict__ out, int n) {
  int i = (blockIdx.x * blockDim.x + threadIdx.x) * 4;
  if (i >= n) return;
  float4 v = *(const float4*)(in + i);
  out[i+0] = (__bf16)v.x; out[i+1] = (__bf16)v.y;
  out[i+2] = (__bf16)v.z; out[i+3] = (__bf16)v.w;
}

// ---------------- transpose fp32 [R][C] -> bf16 [C][R] ----------------
__global__ void k_transpose(const float* __restrict__ in, __bf16* __restrict__ out, int R, int C) {
  __shared__ float tile[32][33];
  int c0 = blockIdx.x * 32, r0 = blockIdx.y * 32;
  int tx = threadIdx.x, ty = threadIdx.y;   // (32, 8)
  #pragma unroll
  for (int i = 0; i < 4; ++i) {
    int r = ty + i*8;
    tile[r][tx] = in[(size_t)(r0 + r)*C + c0 + tx];
  }
  __syncthreads();
  #pragma unroll
  for (int i = 0; i < 4; ++i) {
    int c = ty + i*8;
    out[(size_t)(c0 + c)*R + r0 + tx] = (__bf16)tile[tx][c];
  }
}

// ---------------- GEMM stage: T2 swizzle via pre-swizzled SOURCE (rule #21) ----------------
// GEMM tile rows are 64B -> only bits 4-5 are XOR-safe: mask ((m>>1)&3)<<4 (max 48).
// Spreads the 16 lr-rows over all 8 (parity x granule) bank groups -> 2-way (free).
__device__ __forceinline__ void gemm_stage(const __bf16* __restrict__ A, int lda,
                                           const __bf16* __restrict__ Bt, int ldb,
                                           int m0, int n0, int kt,
                                           __bf16* lA, __bf16* lB) {
  const int tid  = threadIdx.x;
  const int lane = tid & 63;
  const int wid  = tid >> 6;
  #pragma unroll
  for (int c = 0; c < 2; ++c) {
    int chunk = wid*2 + c;               // 0..7
    int bo = chunk*1024 + lane*16;       // linear dest byte offset in tile
    int m  = bo >> 6;                    // 64B per row
    int kb = ((bo & 63) ^ (((m >> 1) & 3) << 4)) >> 1;   // pre-swizzled source col (<=63B, in-tile)
    __builtin_amdgcn_global_load_lds(
      (const __attribute__((address_space(1))) void*)(A + (size_t)(m0 + m)*lda + kt + kb),
      (__attribute__((address_space(3))) void*)(lA + chunk*512), 16, 0, 0);
    __builtin_amdgcn_global_load_lds(
      (const __attribute__((address_space(1))) void*)(Bt + (size_t)(n0 + m)*ldb + kt + kb),
      (__attribute__((address_space(3))) void*)(lB + chunk*512), 16, 0, 0);
  }
}

// ---------------- GEMM core: 2-phase double-buffered 128x128 tile ----------------
__device__ __forceinline__ void gemm_core(const __bf16* __restrict__ A, int lda,
                                          const __bf16* __restrict__ Bt, int ldb,
                                          int K, int m0, int n0,
                                          __bf16* lA, __bf16* lB, f32x4 acc[4][4]) {
  const int lane = threadIdx.x & 63;
  const int wid  = threadIdx.x >> 6;
  const int wm   = (wid >> 1) * 64;
  const int wn   = (wid & 1) * 64;
  const int lr   = lane & 15;
  const int lk   = lane >> 4;

  gemm_stage(A, lda, Bt, ldb, m0, n0, 0, lA, lB);
  __syncthreads();
  int cur = 0;
  for (int kt = 0; kt < K; kt += 32) {
    if (kt + 32 < K)
      gemm_stage(A, lda, Bt, ldb, m0, n0, kt + 32, lA + (cur^1)*4096, lB + (cur^1)*4096);
    const char* cA = (const char*)(lA + cur*4096);
    const char* cB = (const char*)(lB + cur*4096);
    bf16x8 af[4], bfr[4];
    #pragma unroll
    for (int i = 0; i < 4; ++i) {
      int ra = wm + i*16 + lr;
      int rb = wn + i*16 + lr;
      af[i]  = *(const bf16x8*)(cA + ra*64 + ((lk*16) ^ (((ra >> 1) & 3) << 4)));
      bfr[i] = *(const bf16x8*)(cB + rb*64 + ((lk*16) ^ (((rb >> 1) & 3) << 4)));
    }
    #pragma unroll
    for (int mi = 0; mi < 4; ++mi)
      #pragma unroll
      for (int ni = 0; ni < 4; ++ni)
        acc[mi][ni] = __builtin_amdgcn_mfma_f32_16x16x32_bf16(af[mi], bfr[ni], acc[mi][ni], 0, 0, 0);
    __syncthreads();
    cur ^= 1;
  }
}

// ---------------- GEMM1: qkv = xb @ WqkvT + bqkv, scatter to Q(scaled),K,V^T(pi) ----------------
// Blocks are t-uniform (128 | 768). V blocks (t==2) stage their 64x64 wave-patch
// through LDS (transpose + pi fold) -> 16 coalesced 8B stores/thread instead of
// 64 scattered 2B stores. Q/K blocks keep the direct semi-coalesced path.
__global__ __launch_bounds__(256) void k_gemm_qkv(const __bf16* __restrict__ xb,
                                                  const __bf16* __restrict__ wT,
                                                  const float* __restrict__ bias,
                                                  __bf16* __restrict__ qb,
                                                  __bf16* __restrict__ kb,
                                                  __bf16* __restrict__ vtb) {
  __shared__ __align__(16) __bf16 lA[2*128*32];
  __shared__ __align__(16) __bf16 lB[2*128*32];
  f32x4 acc[4][4];
  #pragma unroll
  for (int i = 0; i < 4; ++i)
    #pragma unroll
    for (int j = 0; j < 4; ++j) { f32x4 z = {0.f,0.f,0.f,0.f}; acc[i][j] = z; }

  const int GX = N_QKV/128;  // 18
  int bid = blockIdx.y * GX + blockIdx.x;
  int cpx = (GX * ROWS/128) >> 3;
  int swz = (bid & 7) * cpx + (bid >> 3);
  const int m0 = (swz / GX) * 128, n0 = (swz % GX) * 128;
  gemm_core(xb, D_MODEL, wT, D_MODEL, D_MODEL, m0, n0, lA, lB, acc);

  const int lane = threadIdx.x & 63;
  const int wid  = threadIdx.x >> 6;
  const int wm = (wid >> 1) * 64, wn = (wid & 1) * 64;
  const int lr = lane & 15, lk = lane >> 4;
  const int tt = n0 / D_MODEL;           // block-uniform q/k/v selector

  if (tt < 2) {
    #pragma unroll
    for (int mi = 0; mi < 4; ++mi) {
      #pragma unroll
      for (int ni = 0; ni < 4; ++ni) {
        int col = n0 + wn + ni*16 + lr;
        int r2  = col - tt*D_MODEL;
        int hh  = r2 >> 6, dk = r2 & 63;
        float bv = bias[col];
        #pragma unroll
        for (int j = 0; j < 4; ++j) {
          int row = m0 + wm + mi*16 + lk*4 + j;
          int bb = row >> 11, ss = row & 2047;
          float fv = acc[mi][ni][j] + bv;
          if (tt == 0) qb[(((size_t)bb*NH + hh)*SEQ + ss)*DKH + dk] = (__bf16)(fv * QSCALE);
          else         kb[(((size_t)bb*NH + hh)*SEQ + ss)*DKH + dk] = (__bf16)fv;
        }
      }
    }
  } else {
    // V: per-wave 8KB LDS patch [col64][row64] bf16 (128B rows, XOR-swizzled),
    // then pi-folded transposed read-back -> coalesced global stores.
    // Safe to reuse lA/lB: gemm_core's final __syncthreads has all waves done.
    __bf16* patch = (wid < 2 ? lA : lB) + (wid & 1)*4096;
    #pragma unroll
    for (int ni = 0; ni < 4; ++ni) {
      int cl = ni*16 + lr;
      float bv = bias[n0 + wn + cl];
      int sw2 = (cl & 7) << 4;
      #pragma unroll
      for (int mi = 0; mi < 4; ++mi) {
        bf16x4 v4;
        #pragma unroll
        for (int j = 0; j < 4; ++j) v4[j] = (__bf16)(acc[mi][ni][j] + bv);
        *(bf16x4*)((char*)patch + ((cl*128 + (mi*16 + lk*4)*2) ^ sw2)) = v4;
      }
    }
    // read-back: lane -> (dk_h = lane>>4, p = (lane&15)*4 .. +3)
    // pi: position p holds kv = 16*((p>>2)&1) + 4*((p>>3)&3) + (p&3); aligned-4
    // runs map to aligned-4 runs -> one ds_read_b64 per chunk.
    int hh   = (n0 + wn - 2*D_MODEL) >> 6;   // wave-uniform (wn mult of 64)
    int bb   = m0 >> 11;
    int ssG  = (m0 & 2047) + wm;             // granule-aligned base
    int dk_h = lane >> 4;                    // 0..3
    int pb   = (lane & 15) * 4;              // p = pb..pb+3
    int g    = pb >> 5;                      // granule 0/1
    int tq   = (pb >> 2) & 7;
    int rwb  = g*32 + 16*(tq & 1) + 4*(tq >> 1);   // source kv offset (pi)
    __bf16* vout = vtb + (((size_t)bb*NH + hh)*DKH)*SEQ + ssG + pb;
    #pragma unroll
    for (int r = 0; r < 16; ++r) {
      int dk = r*4 + dk_h;
      bf16x4 v4 = *(const bf16x4*)((const char*)patch + ((dk*128 + rwb*2) ^ ((dk & 7) << 4)));
      *(bf16x4*)(vout + (size_t)dk*SEQ) = v4;
    }
  }
}

// ---------------- GEMM3: out = attn @ WoutT + bout (fp32 out) ----------------
__global__ __launch_bounds__(256) void k_gemm_out(const __bf16* __restrict__ ab,
                                                  const __bf16* __restrict__ wT,
                                                  const float* __restrict__ bias,
                                                  float* __restrict__ out) {
  __shared__ __align__(16) __bf16 lA[2*128*32];
  __shared__ __align__(16) __bf16 lB[2*128*32];
  f32x4 acc[4][4];
  #pragma unroll
  for (int i = 0; i < 4; ++i)
    #pragma unroll
    for (int j = 0; j < 4; ++j) { f32x4 z = {0.f,0.f,0.f,0.f}; acc[i][j] = z; }

  const int GX = D_MODEL/128;  // 6
  int bid = blockIdx.y * GX + blockIdx.x;
  int cpx = (GX * ROWS/128) >> 3;
  int swz = (bid & 7) * cpx + (bid >> 3);
  const int m0 = (swz / GX) * 128, n0 = (swz % GX) * 128;
  gemm_core(ab, D_MODEL, wT, D_MODEL, D_MODEL, m0, n0, lA, lB, acc);

  const int lane = threadIdx.x & 63;
  const int wid  = threadIdx.x >> 6;
  const int wm = (wid >> 1) * 64, wn = (wid & 1) * 64;
  const int lr = lane & 15, lk = lane >> 4;
  #pragma unroll
  for (int mi = 0; mi < 4; ++mi) {
    #pragma unroll
    for (int ni = 0; ni < 4; ++ni) {
      int col = n0 + wn + ni*16 + lr;
      float bv = bias[col];
      #pragma unroll
      for (int j = 0; j < 4; ++j) {
        int row = m0 + wm + mi*16 + lk*4 + j;
        out[(size_t)row*D_MODEL + col] = acc[mi][ni][j] + bv;
      }
    }
  }
}

// Balanced qi map: three permutations of 0..15 with column sums 22/23 (per-CU
// causal work ~constant under round-robin block->CU assignment).
__device__ const int QI_TAB[3][16] = {
  { 0, 1, 2, 3, 4, 5, 6, 7, 8, 9,10,11,12,13,14,15},
  { 8, 9,10,11,12,13,14,15, 1, 2, 3, 4, 5, 6, 7, 0},
  {15,13,11, 9, 6, 4, 2, 0,14,12,10, 7, 5, 3, 1, 8}
};

// ---------------- Flash attention (causal), 8 waves x 16 q-rows (R10 proven) ----------------
__global__ __launch_bounds__(512) void k_attn(const __bf16* __restrict__ q,
                                              const __bf16* __restrict__ k,
                                              const __bf16* __restrict__ vt,
                                              __bf16* __restrict__ out) {
  __shared__ __align__(16) char lsK[2][8192];   // [64 kv][64 d] bf16, swizzled rows
  __shared__ __align__(16) char lsV[2][8192];   // [64 d][64 kv-pi] bf16, swizzled rows

  const int tid  = threadIdx.x;
  const int lane = tid & 63;
  const int wid  = tid >> 6;       // 0..7
  const int lr   = lane & 15;
  const int lk   = lane >> 4;

  const int bh = blockIdx.y;
  const int b  = bh / NH, h = bh - b*NH;
  const int qi  = QI_TAB[blockIdx.y >> 4][blockIdx.x];
  const int qb0 = qi * 128;
  const int q0w = qb0 + wid * 16;

  const __bf16* qh = q + (size_t)bh*SEQ*DKH;
  const char*   kB = (const char*)(k  + (size_t)bh*SEQ*DKH);
  const char*   vB = (const char*)(vt + (size_t)bh*DKH*SEQ);

  bf16x8 bq[2];
  #pragma unroll
  for (int c = 0; c < 2; ++c)
    bq[c] = *(const bf16x8*)(qh + (size_t)(q0w + lr)*DKH + c*32 + lk*8);

  bf16x8 ones;
  #pragma unroll
  for (int i = 0; i < 8; ++i) ones[i] = (__bf16)1.0f;

  f32x4 o[4];
  #pragma unroll
  for (int df = 0; df < 4; ++df) { f32x4 z = {0.f,0.f,0.f,0.f}; o[df] = z; }
  f32x4 o_l = {0.f, 0.f, 0.f, 0.f};
  float m_i = -1e30f;

  const int nt = qb0/64 + 2;

  auto stage = [&](int buf, int kv0) {
    int lb   = wid*1024 + lane*16;
    int row  = lb >> 7;
    int colb = (lb & 127) ^ ((row & 7) << 4);
    __builtin_amdgcn_global_load_lds(
      (const __attribute__((address_space(1))) void*)(kB + (size_t)(kv0 + row)*128 + colb),
      (__attribute__((address_space(3))) void*)(lsK[buf] + wid*1024), 16, 0, 0);
    __builtin_amdgcn_global_load_lds(
      (const __attribute__((address_space(1))) void*)(vB + (size_t)row*(SEQ*2) + (size_t)kv0*2 + colb),
      (__attribute__((address_space(3))) void*)(lsV[buf] + wid*1024), 16, 0, 0);
  };

  stage(0, 0);
  __syncthreads();
  int cur = 0;

  for (int t = 0; t < nt; ++t) {
    const int kv0 = t * 64;
    if (t + 1 < nt) stage(cur ^ 1, kv0 + 64);

    if (kv0 <= q0w + 15) {
      f32x4 sc[4];
      #pragma unroll
      for (int n = 0; n < 4; ++n) { f32x4 z = {0.f,0.f,0.f,0.f}; sc[n] = z; }
      __builtin_amdgcn_s_setprio(1);
      #pragma unroll
      for (int n = 0; n < 4; ++n) {
        int kvl = n*16 + lr;
        const char* kr = lsK[cur] + kvl*128;
        int sw = (kvl & 7) << 4;
        bf16x8 ak0 = *(const bf16x8*)(kr + ((lk*16) ^ sw));
        bf16x8 ak1 = *(const bf16x8*)(kr + ((64 + lk*16) ^ sw));
        sc[n] = __builtin_amdgcn_mfma_f32_16x16x32_bf16(ak0, bq[0], sc[n], 0, 0, 0);
        sc[n] = __builtin_amdgcn_mfma_f32_16x16x32_bf16(ak1, bq[1], sc[n], 0, 0, 0);
      }
      __builtin_amdgcn_s_setprio(0);
      if (kv0 + 63 > q0w) {
        int qrow = q0w + lr;
        #pragma unroll
        for (int n = 0; n < 4; ++n) {
          int kvb = kv0 + n*16 + lk*4;
          #pragma unroll
          for (int j = 0; j < 4; ++j)
            if (kvb + j > qrow) sc[n][j] = -1e30f;
        }
      }
      float a0 = fmaxf(fmaxf(sc[0][0], sc[0][1]), sc[0][2]);
      float a1 = fmaxf(fmaxf(sc[0][3], sc[1][0]), sc[1][1]);
      float a2 = fmaxf(fmaxf(sc[1][2], sc[1][3]), sc[2][0]);
      float a3 = fmaxf(fmaxf(sc[2][1], sc[2][2]), sc[2][3]);
      float a4 = fmaxf(fmaxf(sc[3][0], sc[3][1]), sc[3][2]);
      float pm = fmaxf(fmaxf(fmaxf(a0, a1), a2), fmaxf(fmaxf(a3, a4), sc[3][3]));
      pm = fmaxf(pm, __shfl_xor(pm, 16));
      pm = fmaxf(pm, __shfl_xor(pm, 32));
      if (__any(pm > m_i + 8.0f)) {
        float mn = fmaxf(m_i, pm);
        float alpha = exp2f(m_i - mn);
        m_i = mn;
        #pragma unroll
        for (int j = 0; j < 4; ++j) {
          float av = __shfl(alpha, (lane & 48) | (lk*4 + j));
          o_l[j] *= av;
          #pragma unroll
          for (int df = 0; df < 4; ++df) o[df][j] *= av;
        }
      }
      bf16x8 pa[2];
      #pragma unroll
      for (int n = 0; n < 4; ++n)
        #pragma unroll
        for (int j = 0; j < 4; ++j)
          pa[n >> 1][((n & 1) << 2) | j] = (__bf16)exp2f(sc[n][j] - m_i);
      __builtin_amdgcn_s_setprio(1);
      o_l = __builtin_amdgcn_mfma_f32_16x16x32_bf16(pa[0], ones, o_l, 0, 0, 0);
      o_l = __builtin_amdgcn_mfma_f32_16x16x32_bf16(pa[1], ones, o_l, 0, 0, 0);
      #pragma unroll
      for (int df = 0; df < 4; ++df) {
        int d = df*16 + lr;
        const char* vr = lsV[cur] + d*128;
        int sw = (d & 7) << 4;
        #pragma unroll
        for (int c = 0; c < 2; ++c) {
          bf16x8 bv = *(const bf16x8*)(vr + ((c*64 + lk*16) ^ sw));
          o[df] = __builtin_amdgcn_mfma_f32_16x16x32_bf16(pa[c], bv, o[df], 0, 0, 0);
        }
      }
      __builtin_amdgcn_s_setprio(0);
    }
    __syncthreads();
    cur ^= 1;
  }

  float invl[4];
  #pragma unroll
  for (int j = 0; j < 4; ++j) invl[j] = 1.0f / o_l[j];
  #pragma unroll
  for (int df = 0; df < 4; ++df) {
    int d = df*16 + lr;
    #pragma unroll
    for (int j = 0; j < 4; ++j) {
      int ss = q0w + lk*4 + j;
      out[((size_t)b*SEQ + ss)*D_MODEL + h*DKH + d] = (__bf16)(o[df][j] * invl[j]);
    }
  }
}

// ---------------- launch ----------------
extern "C" void kernel_launch(void* const* d_in, const int* in_sizes, int n_in,
                              void* d_out, int out_size, void* d_ws, size_t ws_size,
                              hipStream_t stream) {
  const float* x    = (const float*)d_in[0];
  /* d_in[1] = causal mask, implemented analytically */
  const float* Wqkv = (const float*)d_in[2];
  const float* bqkv = (const float*)d_in[3];
  const float* Wout = (const float*)d_in[4];
  const float* bout = (const float*)d_in[5];
  float* out = (float*)d_out;

  char* w = (char*)d_ws;
  __bf16* xb    = (__bf16*)w; w += (size_t)ROWS*D_MODEL*2;
  __bf16* wqkvT = (__bf16*)w; w += (size_t)N_QKV*D_MODEL*2;
  __bf16* woutT = (__bf16*)w; w += (size_t)D_MODEL*D_MODEL*2;
  __bf16* qb    = (__bf16*)w; w += (size_t)BATCH*NH*SEQ*DKH*2;
  __bf16* kb    = (__bf16*)w; w += (size_t)BATCH*NH*SEQ*DKH*2;
  __bf16* vtb   = (__bf16*)w; w += (size_t)BATCH*NH*SEQ*DKH*2;
  __bf16* attnb = (__bf16*)w; w += (size_t)ROWS*D_MODEL*2;

  k_convert<<<(ROWS*D_MODEL/4 + 255)/256, 256, 0, stream>>>(x, xb, ROWS*D_MODEL);
  k_transpose<<<dim3(N_QKV/32, D_MODEL/32), dim3(32, 8), 0, stream>>>(Wqkv, wqkvT, D_MODEL, N_QKV);
  k_transpose<<<dim3(D_MODEL/32, D_MODEL/32), dim3(32, 8), 0, stream>>>(Wout, woutT, D_MODEL, D_MODEL);
  k_gemm_qkv<<<dim3(N_QKV/128, ROWS/128), 256, 0, stream>>>(xb, wqkvT, bqkv, qb, kb, vtb);
  k_attn<<<dim3(16, BATCH*NH), 512, 0, stream>>>(qb, kb, vtb, attnb);
  k_gemm_out<<<dim3(D_MODEL/128, ROWS/128), 256, 0, stream>>>(attnb, woutT, bout, out);
}

// Round 14
// 144.020 us; speedup vs baseline: 1.2130x; 1.0684x over previous
//
#include <hip/hip_runtime.h>

typedef __bf16 bf16x8 __attribute__((ext_vector_type(8)));
typedef __bf16 bf16x4 __attribute__((ext_vector_type(4)));
typedef float f32x4 __attribute__((ext_vector_type(4)));

#define D_MODEL 768
#define NH 12
#define DKH 64
#define BATCH 4
#define SEQ 2048
#define ROWS (BATCH*SEQ)   /* 8192 */
#define N_QKV (3*D_MODEL)  /* 2304 */
#define QSCALE 0.18033688f /* 0.125 * log2(e): folds softmax scale + exp2 domain into Q */

// ---------------- convert fp32 -> bf16 ----------------
__global__ void k_convert(const float* __restrict__ in, __bf16* __restrict__ out, int n) {
  int i = (blockIdx.x * blockDim.x + threadIdx.x) * 4;
  if (i >= n) return;
  float4 v = *(const float4*)(in + i);
  out[i+0] = (__bf16)v.x; out[i+1] = (__bf16)v.y;
  out[i+2] = (__bf16)v.z; out[i+3] = (__bf16)v.w;
}

// ---------------- transpose fp32 [R][C] -> bf16 [C][R] ----------------
__global__ void k_transpose(const float* __restrict__ in, __bf16* __restrict__ out, int R, int C) {
  __shared__ float tile[32][33];
  int c0 = blockIdx.x * 32, r0 = blockIdx.y * 32;
  int tx = threadIdx.x, ty = threadIdx.y;   // (32, 8)
  #pragma unroll
  for (int i = 0; i < 4; ++i) {
    int r = ty + i*8;
    tile[r][tx] = in[(size_t)(r0 + r)*C + c0 + tx];
  }
  __syncthreads();
  #pragma unroll
  for (int i = 0; i < 4; ++i) {
    int c = ty + i*8;
    out[(size_t)(c0 + c)*R + r0 + tx] = (__bf16)tile[tx][c];
  }
}

// ---------------- GEMM stage: T2 swizzle via pre-swizzled SOURCE (rule #21) ----------------
// 64B rows -> XOR-safe bits 4-5 only: mask ((m>>1)&3)<<4. Residual 2-way = free.
__device__ __forceinline__ void gemm_stage(const __bf16* __restrict__ A, int lda,
                                           const __bf16* __restrict__ Bt, int ldb,
                                           int m0, int n0, int kt,
                                           __bf16* lA, __bf16* lB) {
  const int tid  = threadIdx.x;
  const int lane = tid & 63;
  const int wid  = tid >> 6;
  #pragma unroll
  for (int c = 0; c < 2; ++c) {
    int chunk = wid*2 + c;               // 0..7
    int bo = chunk*1024 + lane*16;       // linear dest byte offset in tile
    int m  = bo >> 6;                    // 64B per row
    int kb = ((bo & 63) ^ (((m >> 1) & 3) << 4)) >> 1;   // pre-swizzled source col
    __builtin_amdgcn_global_load_lds(
      (const __attribute__((address_space(1))) void*)(A + (size_t)(m0 + m)*lda + kt + kb),
      (__attribute__((address_space(3))) void*)(lA + chunk*512), 16, 0, 0);
    __builtin_amdgcn_global_load_lds(
      (const __attribute__((address_space(1))) void*)(Bt + (size_t)(n0 + m)*ldb + kt + kb),
      (__attribute__((address_space(3))) void*)(lB + chunk*512), 16, 0, 0);
  }
}

// ---------------- one pipelined K-iteration: static BUF/NBUF (no mod, no sched_barrier) ----
// Depth-2 prefetch: tile t's loads were issued 2 iterations ago -> counted
// vmcnt(4) (4 = own in-flight loads of tile t+1) retires them without draining
// the t+1 prefetch. Raw s_barrier publishes tile t across waves; empty memory-
// clobber asm stops ds_reads hoisting above it. Stage of t+2 reuses the buffer
// vacated at the barrier (all waves' t-1 reads completed before entry).
__device__ __forceinline__ void gemm_iter(const __bf16* __restrict__ A, int lda,
                                          const __bf16* __restrict__ Bt, int ldb,
                                          int m0, int n0, int t, int NT,
                                          __bf16* lA, __bf16* lB, int BUF, int NBUF,
                                          int wm, int wn, int lr, int lk,
                                          f32x4 acc[4][4]) {
  if (t + 1 < NT) asm volatile("s_waitcnt vmcnt(4)" ::: "memory");
  else            asm volatile("s_waitcnt vmcnt(0)" ::: "memory");
  __builtin_amdgcn_s_barrier();
  asm volatile("" ::: "memory");
  if (t + 2 < NT)
    gemm_stage(A, lda, Bt, ldb, m0, n0, (t+2)*32, lA + NBUF*4096, lB + NBUF*4096);
  const char* cA = (const char*)(lA + BUF*4096);
  const char* cB = (const char*)(lB + BUF*4096);
  bf16x8 af[4], bfr[4];
  #pragma unroll
  for (int i = 0; i < 4; ++i) {
    int ra = wm + i*16 + lr;
    int rb = wn + i*16 + lr;
    af[i]  = *(const bf16x8*)(cA + ra*64 + ((lk*16) ^ (((ra >> 1) & 3) << 4)));
    bfr[i] = *(const bf16x8*)(cB + rb*64 + ((lk*16) ^ (((rb >> 1) & 3) << 4)));
  }
  #pragma unroll
  for (int mi = 0; mi < 4; ++mi)
    #pragma unroll
    for (int ni = 0; ni < 4; ++ni)
      acc[mi][ni] = __builtin_amdgcn_mfma_f32_16x16x32_bf16(af[mi], bfr[ni], acc[mi][ni], 0, 0, 0);
}

// ---------------- GEMM core: triple-buffer counted-vmcnt pipeline ----------------
// NT = K/32 must be divisible by 3 (K=768 -> 24). LDS 3x(8+8)KB = 48KB -> 3 blocks/CU.
__device__ __forceinline__ void gemm_core(const __bf16* __restrict__ A, int lda,
                                          const __bf16* __restrict__ Bt, int ldb,
                                          int K, int m0, int n0,
                                          __bf16* lA, __bf16* lB, f32x4 acc[4][4]) {
  const int lane = threadIdx.x & 63;
  const int wid  = threadIdx.x >> 6;
  const int wm   = (wid >> 1) * 64;
  const int wn   = (wid & 1) * 64;
  const int lr   = lane & 15;
  const int lk   = lane >> 4;
  const int NT   = K >> 5;

  gemm_stage(A, lda, Bt, ldb, m0, n0, 0,  lA,        lB);
  gemm_stage(A, lda, Bt, ldb, m0, n0, 32, lA + 4096, lB + 4096);

  for (int t = 0; t < NT; t += 3) {
    gemm_iter(A, lda, Bt, ldb, m0, n0, t,   NT, lA, lB, 0, 2, wm, wn, lr, lk, acc);
    gemm_iter(A, lda, Bt, ldb, m0, n0, t+1, NT, lA, lB, 1, 0, wm, wn, lr, lk, acc);
    gemm_iter(A, lda, Bt, ldb, m0, n0, t+2, NT, lA, lB, 2, 1, wm, wn, lr, lk, acc);
  }
}

// ---------------- GEMM1: qkv = xb @ WqkvT + bqkv, scatter to Q(scaled),K,V^T(pi) ----------------
__global__ __launch_bounds__(256) void k_gemm_qkv(const __bf16* __restrict__ xb,
                                                  const __bf16* __restrict__ wT,
                                                  const float* __restrict__ bias,
                                                  __bf16* __restrict__ qb,
                                                  __bf16* __restrict__ kb,
                                                  __bf16* __restrict__ vtb) {
  __shared__ __align__(16) __bf16 lA[3*128*32];
  __shared__ __align__(16) __bf16 lB[3*128*32];
  f32x4 acc[4][4];
  #pragma unroll
  for (int i = 0; i < 4; ++i)
    #pragma unroll
    for (int j = 0; j < 4; ++j) { f32x4 z = {0.f,0.f,0.f,0.f}; acc[i][j] = z; }

  const int GX = N_QKV/128;  // 18
  int bid = blockIdx.y * GX + blockIdx.x;
  int cpx = (GX * ROWS/128) >> 3;
  int swz = (bid & 7) * cpx + (bid >> 3);
  const int m0 = (swz / GX) * 128, n0 = (swz % GX) * 128;
  gemm_core(xb, D_MODEL, wT, D_MODEL, D_MODEL, m0, n0, lA, lB, acc);

  const int lane = threadIdx.x & 63;
  const int wid  = threadIdx.x >> 6;
  const int wm = (wid >> 1) * 64, wn = (wid & 1) * 64;
  const int lr = lane & 15, lk = lane >> 4;
  const int tt = n0 / D_MODEL;           // block-uniform q/k/v selector

  if (tt < 2) {
    #pragma unroll
    for (int mi = 0; mi < 4; ++mi) {
      #pragma unroll
      for (int ni = 0; ni < 4; ++ni) {
        int col = n0 + wn + ni*16 + lr;
        int r2  = col - tt*D_MODEL;
        int hh  = r2 >> 6, dk = r2 & 63;
        float bv = bias[col];
        #pragma unroll
        for (int j = 0; j < 4; ++j) {
          int row = m0 + wm + mi*16 + lk*4 + j;
          int bb = row >> 11, ss = row & 2047;
          float fv = acc[mi][ni][j] + bv;
          if (tt == 0) qb[(((size_t)bb*NH + hh)*SEQ + ss)*DKH + dk] = (__bf16)(fv * QSCALE);
          else         kb[(((size_t)bb*NH + hh)*SEQ + ss)*DKH + dk] = (__bf16)fv;
        }
      }
    }
  } else {
    // V: per-wave 8KB LDS patch [col64][row64] bf16 (128B rows, XOR-swizzled),
    // then pi-folded transposed read-back -> coalesced global stores.
    __syncthreads();   // all waves past their last tile-buf reads
    __bf16* patch = (wid < 2 ? lA : lB) + (wid & 1)*4096;
    #pragma unroll
    for (int ni = 0; ni < 4; ++ni) {
      int cl = ni*16 + lr;
      float bv = bias[n0 + wn + cl];
      int sw2 = (cl & 7) << 4;
      #pragma unroll
      for (int mi = 0; mi < 4; ++mi) {
        bf16x4 v4;
        #pragma unroll
        for (int j = 0; j < 4; ++j) v4[j] = (__bf16)(acc[mi][ni][j] + bv);
        *(bf16x4*)((char*)patch + ((cl*128 + (mi*16 + lk*4)*2) ^ sw2)) = v4;
      }
    }
    int hh   = (n0 + wn - 2*D_MODEL) >> 6;   // wave-uniform
    int bb   = m0 >> 11;
    int ssG  = (m0 & 2047) + wm;             // granule-aligned base
    int dk_h = lane >> 4;                    // 0..3
    int pb   = (lane & 15) * 4;              // p = pb..pb+3
    int g    = pb >> 5;                      // granule 0/1
    int tq   = (pb >> 2) & 7;
    int rwb  = g*32 + 16*(tq & 1) + 4*(tq >> 1);   // source kv offset (pi)
    __bf16* vout = vtb + (((size_t)bb*NH + hh)*DKH)*SEQ + ssG + pb;
    #pragma unroll
    for (int r = 0; r < 16; ++r) {
      int dk = r*4 + dk_h;
      bf16x4 v4 = *(const bf16x4*)((const char*)patch + ((dk*128 + rwb*2) ^ ((dk & 7) << 4)));
      *(bf16x4*)(vout + (size_t)dk*SEQ) = v4;
    }
  }
}

// ---------------- GEMM3: out = attn @ WoutT + bout (fp32 out) ----------------
__global__ __launch_bounds__(256) void k_gemm_out(const __bf16* __restrict__ ab,
                                                  const __bf16* __restrict__ wT,
                                                  const float* __restrict__ bias,
                                                  float* __restrict__ out) {
  __shared__ __align__(16) __bf16 lA[3*128*32];
  __shared__ __align__(16) __bf16 lB[3*128*32];
  f32x4 acc[4][4];
  #pragma unroll
  for (int i = 0; i < 4; ++i)
    #pragma unroll
    for (int j = 0; j < 4; ++j) { f32x4 z = {0.f,0.f,0.f,0.f}; acc[i][j] = z; }

  const int GX = D_MODEL/128;  // 6
  int bid = blockIdx.y * GX + blockIdx.x;
  int cpx = (GX * ROWS/128) >> 3;
  int swz = (bid & 7) * cpx + (bid >> 3);
  const int m0 = (swz / GX) * 128, n0 = (swz % GX) * 128;
  gemm_core(ab, D_MODEL, wT, D_MODEL, D_MODEL, m0, n0, lA, lB, acc);

  const int lane = threadIdx.x & 63;
  const int wid  = threadIdx.x >> 6;
  const int wm = (wid >> 1) * 64, wn = (wid & 1) * 64;
  const int lr = lane & 15, lk = lane >> 4;
  #pragma unroll
  for (int mi = 0; mi < 4; ++mi) {
    #pragma unroll
    for (int ni = 0; ni < 4; ++ni) {
      int col = n0 + wn + ni*16 + lr;
      float bv = bias[col];
      #pragma unroll
      for (int j = 0; j < 4; ++j) {
        int row = m0 + wm + mi*16 + lk*4 + j;
        out[(size_t)row*D_MODEL + col] = acc[mi][ni][j] + bv;
      }
    }
  }
}

// Balanced qi map: three permutations of 0..15 with column sums 22/23.
__device__ const int QI_TAB[3][16] = {
  { 0, 1, 2, 3, 4, 5, 6, 7, 8, 9,10,11,12,13,14,15},
  { 8, 9,10,11,12,13,14,15, 1, 2, 3, 4, 5, 6, 7, 0},
  {15,13,11, 9, 6, 4, 2, 0,14,12,10, 7, 5, 3, 1, 8}
};

// ---------------- Flash attention (causal), 8 waves x 16 q-rows (R13 unchanged) ----------------
__global__ __launch_bounds__(512) void k_attn(const __bf16* __restrict__ q,
                                              const __bf16* __restrict__ k,
                                              const __bf16* __restrict__ vt,
                                              __bf16* __restrict__ out) {
  __shared__ __align__(16) char lsK[2][8192];   // [64 kv][64 d] bf16, swizzled rows
  __shared__ __align__(16) char lsV[2][8192];   // [64 d][64 kv-pi] bf16, swizzled rows

  const int tid  = threadIdx.x;
  const int lane = tid & 63;
  const int wid  = tid >> 6;       // 0..7
  const int lr   = lane & 15;
  const int lk   = lane >> 4;

  const int bh = blockIdx.y;
  const int b  = bh / NH, h = bh - b*NH;
  const int qi  = QI_TAB[blockIdx.y >> 4][blockIdx.x];
  const int qb0 = qi * 128;
  const int q0w = qb0 + wid * 16;

  const __bf16* qh = q + (size_t)bh*SEQ*DKH;
  const char*   kB = (const char*)(k  + (size_t)bh*SEQ*DKH);
  const char*   vB = (const char*)(vt + (size_t)bh*DKH*SEQ);

  bf16x8 bq[2];
  #pragma unroll
  for (int c = 0; c < 2; ++c)
    bq[c] = *(const bf16x8*)(qh + (size_t)(q0w + lr)*DKH + c*32 + lk*8);

  bf16x8 ones;
  #pragma unroll
  for (int i = 0; i < 8; ++i) ones[i] = (__bf16)1.0f;

  f32x4 o[4];
  #pragma unroll
  for (int df = 0; df < 4; ++df) { f32x4 z = {0.f,0.f,0.f,0.f}; o[df] = z; }
  f32x4 o_l = {0.f, 0.f, 0.f, 0.f};
  float m_i = -1e30f;

  const int nt = qb0/64 + 2;

  auto stage = [&](int buf, int kv0) {
    int lb   = wid*1024 + lane*16;
    int row  = lb >> 7;
    int colb = (lb & 127) ^ ((row & 7) << 4);
    __builtin_amdgcn_global_load_lds(
      (const __attribute__((address_space(1))) void*)(kB + (size_t)(kv0 + row)*128 + colb),
      (__attribute__((address_space(3))) void*)(lsK[buf] + wid*1024), 16, 0, 0);
    __builtin_amdgcn_global_load_lds(
      (const __attribute__((address_space(1))) void*)(vB + (size_t)row*(SEQ*2) + (size_t)kv0*2 + colb),
      (__attribute__((address_space(3))) void*)(lsV[buf] + wid*1024), 16, 0, 0);
  };

  stage(0, 0);
  __syncthreads();
  int cur = 0;

  for (int t = 0; t < nt; ++t) {
    const int kv0 = t * 64;
    if (t + 1 < nt) stage(cur ^ 1, kv0 + 64);

    if (kv0 <= q0w + 15) {
      f32x4 sc[4];
      #pragma unroll
      for (int n = 0; n < 4; ++n) { f32x4 z = {0.f,0.f,0.f,0.f}; sc[n] = z; }
      __builtin_amdgcn_s_setprio(1);
      #pragma unroll
      for (int n = 0; n < 4; ++n) {
        int kvl = n*16 + lr;
        const char* kr = lsK[cur] + kvl*128;
        int sw = (kvl & 7) << 4;
        bf16x8 ak0 = *(const bf16x8*)(kr + ((lk*16) ^ sw));
        bf16x8 ak1 = *(const bf16x8*)(kr + ((64 + lk*16) ^ sw));
        sc[n] = __builtin_amdgcn_mfma_f32_16x16x32_bf16(ak0, bq[0], sc[n], 0, 0, 0);
        sc[n] = __builtin_amdgcn_mfma_f32_16x16x32_bf16(ak1, bq[1], sc[n], 0, 0, 0);
      }
      __builtin_amdgcn_s_setprio(0);
      if (kv0 + 63 > q0w) {
        int qrow = q0w + lr;
        #pragma unroll
        for (int n = 0; n < 4; ++n) {
          int kvb = kv0 + n*16 + lk*4;
          #pragma unroll
          for (int j = 0; j < 4; ++j)
            if (kvb + j > qrow) sc[n][j] = -1e30f;
        }
      }
      float a0 = fmaxf(fmaxf(sc[0][0], sc[0][1]), sc[0][2]);
      float a1 = fmaxf(fmaxf(sc[0][3], sc[1][0]), sc[1][1]);
      float a2 = fmaxf(fmaxf(sc[1][2], sc[1][3]), sc[2][0]);
      float a3 = fmaxf(fmaxf(sc[2][1], sc[2][2]), sc[2][3]);
      float a4 = fmaxf(fmaxf(sc[3][0], sc[3][1]), sc[3][2]);
      float pm = fmaxf(fmaxf(fmaxf(a0, a1), a2), fmaxf(fmaxf(a3, a4), sc[3][3]));
      pm = fmaxf(pm, __shfl_xor(pm, 16));
      pm = fmaxf(pm, __shfl_xor(pm, 32));
      if (__any(pm > m_i + 8.0f)) {
        float mn = fmaxf(m_i, pm);
        float alpha = exp2f(m_i - mn);
        m_i = mn;
        #pragma unroll
        for (int j = 0; j < 4; ++j) {
          float av = __shfl(alpha, (lane & 48) | (lk*4 + j));
          o_l[j] *= av;
          #pragma unroll
          for (int df = 0; df < 4; ++df) o[df][j] *= av;
        }
      }
      bf16x8 pa[2];
      #pragma unroll
      for (int n = 0; n < 4; ++n)
        #pragma unroll
        for (int j = 0; j < 4; ++j)
          pa[n >> 1][((n & 1) << 2) | j] = (__bf16)exp2f(sc[n][j] - m_i);
      __builtin_amdgcn_s_setprio(1);
      o_l = __builtin_amdgcn_mfma_f32_16x16x32_bf16(pa[0], ones, o_l, 0, 0, 0);
      o_l = __builtin_amdgcn_mfma_f32_16x16x32_bf16(pa[1], ones, o_l, 0, 0, 0);
      #pragma unroll
      for (int df = 0; df < 4; ++df) {
        int d = df*16 + lr;
        const char* vr = lsV[cur] + d*128;
        int sw = (d & 7) << 4;
        #pragma unroll
        for (int c = 0; c < 2; ++c) {
          bf16x8 bv = *(const bf16x8*)(vr + ((c*64 + lk*16) ^ sw));
          o[df] = __builtin_amdgcn_mfma_f32_16x16x32_bf16(pa[c], bv, o[df], 0, 0, 0);
        }
      }
      __builtin_amdgcn_s_setprio(0);
    }
    __syncthreads();
    cur ^= 1;
  }

  float invl[4];
  #pragma unroll
  for (int j = 0; j < 4; ++j) invl[j] = 1.0f / o_l[j];
  #pragma unroll
  for (int df = 0; df < 4; ++df) {
    int d = df*16 + lr;
    #pragma unroll
    for (int j = 0; j < 4; ++j) {
      int ss = q0w + lk*4 + j;
      out[((size_t)b*SEQ + ss)*D_MODEL + h*DKH + d] = (__bf16)(o[df][j] * invl[j]);
    }
  }
}

// ---------------- launch ----------------
extern "C" void kernel_launch(void* const* d_in, const int* in_sizes, int n_in,
                              void* d_out, int out_size, void* d_ws, size_t ws_size,
                              hipStream_t stream) {
  const float* x    = (const float*)d_in[0];
  /* d_in[1] = causal mask, implemented analytically */
  const float* Wqkv = (const float*)d_in[2];
  const float* bqkv = (const float*)d_in[3];
  const float* Wout = (const float*)d_in[4];
  const float* bout = (const float*)d_in[5];
  float* out = (float*)d_out;

  char* w = (char*)d_ws;
  __bf16* xb    = (__bf16*)w; w += (size_t)ROWS*D_MODEL*2;
  __bf16* wqkvT = (__bf16*)w; w += (size_t)N_QKV*D_MODEL*2;
  __bf16* woutT = (__bf16*)w; w += (size_t)D_MODEL*D_MODEL*2;
  __bf16* qb    = (__bf16*)w; w += (size_t)BATCH*NH*SEQ*DKH*2;
  __bf16* kb    = (__bf16*)w; w += (size_t)BATCH*NH*SEQ*DKH*2;
  __bf16* vtb   = (__bf16*)w; w += (size_t)BATCH*NH*SEQ*DKH*2;
  __bf16* attnb = (__bf16*)w; w += (size_t)ROWS*D_MODEL*2;

  k_convert<<<(ROWS*D_MODEL/4 + 255)/256, 256, 0, stream>>>(x, xb, ROWS*D_MODEL);
  k_transpose<<<dim3(N_QKV/32, D_MODEL/32), dim3(32, 8), 0, stream>>>(Wqkv, wqkvT, D_MODEL, N_QKV);
  k_transpose<<<dim3(D_MODEL/32, D_MODEL/32), dim3(32, 8), 0, stream>>>(Wout, woutT, D_MODEL, D_MODEL);
  k_gemm_qkv<<<dim3(N_QKV/128, ROWS/128), 256, 0, stream>>>(xb, wqkvT, bqkv, qb, kb, vtb);
  k_attn<<<dim3(16, BATCH*NH), 512, 0, stream>>>(qb, kb, vtb, attnb);
  k_gemm_out<<<dim3(D_MODEL/128, ROWS/128), 256, 0, stream>>>(attnb, woutT, bout, out);
}